// Round 13
// baseline (843.122 us; speedup 1.0000x reference)
//
#include <hip/hip_runtime.h>
#include <hip/hip_bf16.h>

// Capsule routing in ONE kernel: 1024 blocks x 256 thr, __launch_bounds__(256,4)
// guarantees 4 blocks/CU x 256 CU = 1024 co-resident -> DIY device-scope grid
// barrier (atomicAdd + threadfence, rocPRIM pattern) is deadlock-free.
// Phases: P0 prep(u->u_bf,colsum slabs) | P1 vjt0 | P2 route0 | P3 vjt1 |
//         P4 route1 | P5 out.  5 barriers replace 5 launch gaps (~12us each).

constexpr int B = 32, N = 1024, K = 512, O = 32, D = 64, F = 2048;
constexpr int NT = 32;   // n-tile -> 32 slabs per b
constexpr int ST = 72;   // LDS u16 row stride
constexpr unsigned NBLK = 1024;

typedef __attribute__((ext_vector_type(8))) short bf16x8;
typedef __attribute__((ext_vector_type(4))) float f32x4;

__device__ inline unsigned int pk_hi(float x, float y) {
  union { __hip_bfloat162 h; unsigned int u; } c;
  c.h = __float22bfloat162_rn(float2{x, y});
  return c.u;
}
__device__ inline unsigned short bf16_1(float x) {
  return (unsigned short)(pk_hi(x, 0.f) & 0xffffu);
}
__device__ inline void split2(float x, unsigned short& h, unsigned short& l) {
  h = bf16_1(x);
  l = bf16_1(x - __uint_as_float((unsigned int)h << 16));
}
__device__ inline float bf2f(unsigned short h) {
  return __uint_as_float((unsigned int)h << 16);
}
__device__ inline int swz(int r) { return ((r >> 3) & 7) << 3; }

__device__ inline bf16x8 frag_row(const unsigned short* p, int r, int k0) {
  return *(const bf16x8*)&p[r * ST + (k0 ^ swz(r))];
}
__device__ inline bf16x8 frag_col(const unsigned short* p, int c, int n0) {
  bf16x8 f;
#pragma unroll
  for (int j = 0; j < 8; j++) {
    int n = n0 + j;
    f[j] = (short)p[n * ST + (c ^ swz(n))];
  }
  return f;
}

// device-scope grid barrier; requires all NBLK blocks resident.
__device__ inline void gridbar(unsigned* bar, int idx) {
  __syncthreads();
  if (threadIdx.x == 0) {
    __threadfence();              // release: wbL2 so other XCDs see our stores
    atomicAdd(&bar[idx], 1u);
    while (__hip_atomic_load(&bar[idx], __ATOMIC_RELAXED,
                             __HIP_MEMORY_SCOPE_AGENT) < NBLK)
      __builtin_amdgcn_s_sleep(8);
    __threadfence();              // acquire: invalidate L1/L2 reads
  }
  __syncthreads();
}

// ---- vjt phase (256 thr): slab-sum -> vj -> ssq store -> t bf16 hi/lo ----
__device__ inline void vjt_phase(int bid, int tid, char* smem, int slot,
                                 const unsigned short* __restrict__ Sp,
                                 const float* __restrict__ cs_part,
                                 const float* __restrict__ W,
                                 float* __restrict__ ssq_part,
                                 unsigned short* __restrict__ t_hi_g,
                                 unsigned short* __restrict__ t_lo_g) {
  float* s_s = (float*)smem;                  // 2048 B
  float* red = (float*)(smem + 2048);         // 768 B
  float* vs = (float*)(smem + 2048 + 768);    // 256 B
  int b = bid >> 5, o = bid & 31;
  for (int k = tid; k < K; k += 256) {
    float a = 0.f;
    if (slot == 0) {
      const float* base = cs_part + (size_t)b * 32 * K + k;
#pragma unroll
      for (int nt = 0; nt < 32; nt++) a += base[(size_t)nt * K];
    } else {
      const unsigned short* base = Sp + ((size_t)b * NT * O + o) * K + k;
#pragma unroll
      for (int nt = 0; nt < NT; nt++) a += bf2f(base[(size_t)nt * O * K]);
    }
    s_s[k] = a;
  }
  __syncthreads();
  int d = tid & 63, ks = tid >> 6;  // 4-way k split
  float acc = 0.f;
  const float* Wc = W + (size_t)o * D + d;
  for (int k = ks * 128; k < ks * 128 + 128; k += 4) {
    acc += s_s[k] * Wc[(size_t)k * F] + s_s[k + 1] * Wc[(size_t)(k + 1) * F] +
           s_s[k + 2] * Wc[(size_t)(k + 2) * F] + s_s[k + 3] * Wc[(size_t)(k + 3) * F];
  }
  if (ks) red[(ks - 1) * 64 + d] = acc;
  __syncthreads();
  if (ks == 0) {
    acc += red[d] + red[64 + d] + red[128 + d];
    vs[d] = acc;
    float ss = acc * acc;
#pragma unroll
    for (int m = 32; m >= 1; m >>= 1) ss += __shfl_xor(ss, m, 64);
    if (d == 0) ssq_part[slot * 1024 + bid] = ss;
  }
  __syncthreads();
  {  // t = W_o @ vj, bf16 hi/lo; wave: 128 rows, 8 lanes/row (coalesced)
    int wave = tid >> 6, lane = tid & 63;
    int rr = lane >> 3, dc = lane & 7;
    float4 va = *(const float4*)&vs[dc * 8];
    float4 vb = *(const float4*)&vs[dc * 8 + 4];
#pragma unroll
    for (int i = 0; i < 16; i++) {
      int kk = wave * 128 + i * 8 + rr;
      const float* Wr = W + (size_t)kk * F + o * 64 + dc * 8;
      float4 wa = *(const float4*)Wr;
      float4 wb = *(const float4*)(Wr + 4);
      float p = wa.x * va.x + wa.y * va.y + wa.z * va.z + wa.w * va.w +
                wb.x * vb.x + wb.y * vb.y + wb.z * vb.z + wb.w * vb.w;
      p += __shfl_xor(p, 1, 64);
      p += __shfl_xor(p, 2, 64);
      p += __shfl_xor(p, 4, 64);
      if (dc == 0) {
        unsigned short h, l;
        split2(p, h, l);
        t_hi_g[(size_t)bid * K + kk] = h;
        t_lo_g[(size_t)bid * K + kk] = l;
      }
    }
  }
}

// ---- route phase (256 thr): bb=(t.u^T)/nrm -> softmax_o -> Spart = Wv.u ----
__device__ inline void route_phase(int bid, int tid, char* smem, int slot,
                                   const unsigned short* __restrict__ t_hi_g,
                                   const unsigned short* __restrict__ t_lo_g,
                                   const unsigned short* __restrict__ u_bf,
                                   const float* __restrict__ ssq_part,
                                   unsigned short* __restrict__ Sp) {
  unsigned short* u_hi = (unsigned short*)smem;             // 4608 B
  unsigned short* t_hi = (unsigned short*)(smem + 4608);    // 4608 B
  unsigned short* t_lo = (unsigned short*)(smem + 9216);    // 4608 B
  float* wv = (float*)(smem + 13824);                       // 4608 B
  float* psum = (float*)(smem + 18432);                     // 1152 B
  float* mbuf = (float*)(smem + 19584);                     // 144 B
  unsigned short* wvh = t_hi;  // alias: t dead after phase 1
  unsigned short* wvl = t_lo;

  const int b = bid >> 5, ntile = bid & 31, n0 = ntile * 32;
  const int lane = tid & 63, wave = tid >> 6;
  const int m = lane & 15, oct = lane >> 4;
  const unsigned short* ubf = u_bf + ((size_t)b * N + n0) * K;
  const unsigned short* thg = t_hi_g + (size_t)b * O * K;
  const unsigned short* tlg = t_lo_g + (size_t)b * O * K;

  // staging: 256 thr = 32 rows x 8 col-groups, ONE uint4 each (bug fix: was 2x)
  const int sr = tid >> 3, sc8 = (tid & 7) * 8;
  const int scs = sc8 ^ swz(sr);

  // phase 1: bb[32o][32n] = t . u^T
  const int mo = wave & 1, nt = wave >> 1;
  f32x4 accb = {0.f, 0.f, 0.f, 0.f};
  for (int kc = 0; kc < K; kc += 64) {
    __syncthreads();
    {
      const size_t go = (size_t)sr * K + kc + sc8;
      *(uint4*)&t_hi[sr * ST + scs] = *(const uint4*)&thg[go];
      *(uint4*)&t_lo[sr * ST + scs] = *(const uint4*)&tlg[go];
      *(uint4*)&u_hi[sr * ST + scs] = *(const uint4*)&ubf[go];
    }
    __syncthreads();
#pragma unroll
    for (int ks = 0; ks < 64; ks += 32) {
      bf16x8 ah = frag_row(t_hi, mo * 16 + m, ks + oct * 8);
      bf16x8 al = frag_row(t_lo, mo * 16 + m, ks + oct * 8);
      bf16x8 bh = frag_row(u_hi, nt * 16 + m, ks + oct * 8);
      accb = __builtin_amdgcn_mfma_f32_16x16x32_bf16(ah, bh, accb, 0, 0, 0);
      accb = __builtin_amdgcn_mfma_f32_16x16x32_bf16(al, bh, accb, 0, 0, 0);
    }
  }
  __syncthreads();
  // global-norm reduction from ssq_part (1024 entries)
  {
    const float* sp = ssq_part + slot * 1024;
    float sa = 0.f;
#pragma unroll
    for (int j = 0; j < 4; j++) sa += sp[tid + j * 256];
    psum[tid] = sa;
    __syncthreads();
    if (tid < 64) {
      float s = psum[tid] + psum[tid + 64] + psum[tid + 128] + psum[tid + 192];
#pragma unroll
      for (int mm = 32; mm >= 1; mm >>= 1) s += __shfl_xor(s, mm, 64);
      if (tid == 0) mbuf[0] = rsqrtf(fmaxf(s, 1e-12f));
    }
    __syncthreads();
  }
  const float nrm_inv = mbuf[0];
  __syncthreads();
#pragma unroll
  for (int r = 0; r < 4; r++)  // D: col=m (n), row=oct*4+r (o)
    wv[(mo * 16 + oct * 4 + r) * 36 + nt * 16 + m] = accb[r] * nrm_inv;
  __syncthreads();
  // softmax over o: n=tid&31, g=tid>>5 owns 4 o's
  {
    int n = tid & 31, g = tid >> 5;
    float m4 = -1e30f;
#pragma unroll
    for (int j = 0; j < 4; j++) m4 = fmaxf(m4, wv[(g * 4 + j) * 36 + n]);
    psum[g * 36 + n] = m4;
    __syncthreads();
    if (tid < 32) {
      float mx = psum[tid];
#pragma unroll
      for (int gg = 1; gg < 8; gg++) mx = fmaxf(mx, psum[gg * 36 + tid]);
      mbuf[tid] = mx;
    }
    __syncthreads();
    float mx = mbuf[n];
    float s4 = 0.f;
#pragma unroll
    for (int j = 0; j < 4; j++) {
      float e = __expf(wv[(g * 4 + j) * 36 + n] - mx);
      wv[(g * 4 + j) * 36 + n] = e;
      s4 += e;
    }
    psum[g * 36 + n] = s4;
    __syncthreads();
    if (tid < 32) {
      float s = 0.f;
#pragma unroll
      for (int gg = 0; gg < 8; gg++) s += psum[gg * 36 + tid];
      mbuf[tid] = 1.f / s;
    }
    __syncthreads();
    float inv = mbuf[n];
#pragma unroll
    for (int j = 0; j < 4; j++) {
      unsigned short h, l;
      split2(wv[(g * 4 + j) * 36 + n] * inv, h, l);
      wvh[(g * 4 + j) * ST + n] = h;
      wvl[(g * 4 + j) * ST + n] = l;
    }
  }
  __syncthreads();
  // phase 2: Spart = Wv . u (bf16 stores, no atomics)
  const int mo2 = wave & 1, kp = wave >> 1;
  const int o0 = mo2 * 16;
  bf16x8 a_h = *(const bf16x8*)&wvh[(o0 + m) * ST + oct * 8];
  bf16x8 a_l = *(const bf16x8*)&wvl[(o0 + m) * ST + oct * 8];
  unsigned short* Sb = Sp + ((size_t)b * NT + ntile) * O * K;
  for (int kc = 0; kc < K; kc += 64) {
    __syncthreads();
    *(uint4*)&u_hi[sr * ST + scs] = *(const uint4*)&ubf[(size_t)sr * K + kc + sc8];
    __syncthreads();
#pragma unroll
    for (int kt = kp * 2; kt < kp * 2 + 2; kt++) {
      int c = kt * 16 + m;
      bf16x8 bh = frag_col(u_hi, c, oct * 8);
      f32x4 acs = {0.f, 0.f, 0.f, 0.f};
      acs = __builtin_amdgcn_mfma_f32_16x16x32_bf16(a_h, bh, acs, 0, 0, 0);
      acs = __builtin_amdgcn_mfma_f32_16x16x32_bf16(a_l, bh, acs, 0, 0, 0);
#pragma unroll
      for (int r = 0; r < 4; r++)
        Sb[(size_t)(o0 + oct * 4 + r) * K + kc + c] = bf16_1(acs[r]);
    }
  }
}

__global__ __launch_bounds__(256, 4) void k_fused(
    const float* __restrict__ u, const float* __restrict__ W,
    float* __restrict__ out, unsigned short* __restrict__ Sp,
    unsigned short* __restrict__ u_bf, unsigned short* __restrict__ t_hi_g,
    unsigned short* __restrict__ t_lo_g, float* __restrict__ cs_part,
    float* __restrict__ ssq_part, unsigned* __restrict__ bar) {
  __shared__ __align__(16) char smem[19728];
  const int bid = blockIdx.x, tid = threadIdx.x;

  // ---- P0: prep (u -> u_bf + colsum slabs) ----
  {
    float4* red4 = (float4*)smem;
    int b = bid >> 5, ntile = bid & 31, n0 = ntile * 32;
    int kq = (tid & 127) * 4, ng = tid >> 7;
    const float* ub = u + ((size_t)b * N + n0 + ng * 16) * K + kq;
    unsigned short* ubf = u_bf + ((size_t)b * N + n0 + ng * 16) * K + kq;
    float4 a = {0.f, 0.f, 0.f, 0.f};
#pragma unroll
    for (int nn = 0; nn < 16; nn++) {
      float4 v = *(const float4*)&ub[(size_t)nn * K];
      a.x += v.x; a.y += v.y; a.z += v.z; a.w += v.w;
      uint2 p;
      p.x = pk_hi(v.x, v.y);
      p.y = pk_hi(v.z, v.w);
      *(uint2*)&ubf[(size_t)nn * K] = p;
    }
    if (ng) red4[tid & 127] = a;
    __syncthreads();
    if (!ng) {
      float4 o4 = red4[tid];
      float* cs = cs_part + ((size_t)b * 32 + ntile) * K + kq;
      cs[0] = (a.x + o4.x) * (1.f / 32.f);
      cs[1] = (a.y + o4.y) * (1.f / 32.f);
      cs[2] = (a.z + o4.z) * (1.f / 32.f);
      cs[3] = (a.w + o4.w) * (1.f / 32.f);
    }
  }
  gridbar(bar, 0);
  // ---- P1: vjt iter0 ----
  vjt_phase(bid, tid, smem, 0, Sp, cs_part, W, ssq_part, t_hi_g, t_lo_g);
  gridbar(bar, 1);
  // ---- P2: route iter0 ----
  route_phase(bid, tid, smem, 0, t_hi_g, t_lo_g, u_bf, ssq_part, Sp);
  gridbar(bar, 2);
  // ---- P3: vjt iter1 ----
  vjt_phase(bid, tid, smem, 1, Sp, cs_part, W, ssq_part, t_hi_g, t_lo_g);
  gridbar(bar, 3);
  // ---- P4: route iter1 ----
  route_phase(bid, tid, smem, 1, t_hi_g, t_lo_g, u_bf, ssq_part, Sp);
  gridbar(bar, 4);
  // ---- P5: out (vj from slabs -> squash) ----
  {
    float* s_s = (float*)smem;
    float* red = (float*)(smem + 2048);
    int b = bid >> 5, o = bid & 31;
    for (int k = tid; k < K; k += 256) {
      const unsigned short* base = Sp + ((size_t)b * NT * O + o) * K + k;
      float a = 0.f;
#pragma unroll
      for (int nt = 0; nt < NT; nt++) a += bf2f(base[(size_t)nt * O * K]);
      s_s[k] = a;
    }
    __syncthreads();
    int d = tid & 63, ks = tid >> 6;
    float acc = 0.f;
    const float* Wc = W + (size_t)o * D + d;
    for (int k = ks * 128; k < ks * 128 + 128; k += 4) {
      acc += s_s[k] * Wc[(size_t)k * F] + s_s[k + 1] * Wc[(size_t)(k + 1) * F] +
             s_s[k + 2] * Wc[(size_t)(k + 2) * F] +
             s_s[k + 3] * Wc[(size_t)(k + 3) * F];
    }
    if (ks) red[(ks - 1) * 64 + d] = acc;
    __syncthreads();
    if (ks == 0) {
      acc += red[d] + red[64 + d] + red[128 + d];
      float ss = acc * acc;
#pragma unroll
      for (int mm = 32; mm >= 1; mm >>= 1) ss += __shfl_xor(ss, mm, 64);
      float s = ss + 1e-7f;
      out[(size_t)bid * D + d] = (sqrtf(s) / (0.5f + s)) * acc;
    }
  }
}

extern "C" void kernel_launch(void* const* d_in, const int* in_sizes, int n_in,
                              void* d_out, int out_size, void* d_ws, size_t ws_size,
                              hipStream_t stream) {
  const float* u = (const float*)d_in[0];  // [B,N,K] f32
  const float* W = (const float*)d_in[1];  // [K,F] f32
  float* out = (float*)d_out;              // [B,O,D] f32

  char* ws = (char*)d_ws;
  unsigned* bar = (unsigned*)ws;                            // 32 u32
  unsigned short* Sp = (unsigned short*)(ws + 128);         // B*NT*O*K u16 (33.5MB)
  unsigned short* u_bf = Sp + (size_t)B * NT * O * K;       // B*N*K u16 (33.5MB)
  unsigned short* t_hi = u_bf + (size_t)B * N * K;          // B*O*K u16 (1MB)
  unsigned short* t_lo = t_hi + (size_t)B * O * K;          // B*O*K u16
  float* cs_part = (float*)(t_lo + (size_t)B * O * K);      // B*32*K f32 (2MB)
  float* ssq_part = cs_part + (size_t)B * 32 * K;           // 2048 f32

  hipMemsetAsync(bar, 0, 32 * sizeof(unsigned), stream);
  k_fused<<<NBLK, 256, 0, stream>>>(u, W, out, Sp, u_bf, t_hi, t_lo, cs_part,
                                    ssq_part, bar);
}

// Round 14
// 186.915 us; speedup vs baseline: 4.5107x; 4.5107x over previous
//
#include <hip/hip_runtime.h>
#include <hip/hip_bf16.h>

// Capsule routing; u_hat never materialized. Per iter:
//   vjt: vj = S@W_o -> ssq_part (plain store); t = W_o@vj as bf16 hi/lo
//   route: bb = (t.u^T)/nrm -> softmax_o -> Spart[nt] = Wv.u (MFMA bf16 hi/lo)
// R12 skeleton (measured best, 190us) with the staging double-write bug fixed:
// each thread stages exactly ONE uint4 per buffer per chunk (was two).
// NOTE (R13): in-kernel grid barriers (threadfence+atomic spin) cost 130us+
// each on CDNA4 (cache invalidation) -- launch gaps are cheaper. Keep 6 kernels.

constexpr int B = 32, N = 1024, K = 512, O = 32, D = 64, F = 2048;
constexpr int NT = 32;   // n-tile -> 32 slabs per b
constexpr int ST = 72;   // LDS u16 row stride: 144B, 16B-aligned, b128-friendly

typedef __attribute__((ext_vector_type(8))) short bf16x8;
typedef __attribute__((ext_vector_type(4))) float f32x4;

__device__ inline unsigned int pk_hi(float x, float y) {
  union { __hip_bfloat162 h; unsigned int u; } c;
  c.h = __float22bfloat162_rn(float2{x, y});
  return c.u;
}
__device__ inline unsigned short bf16_1(float x) {
  return (unsigned short)(pk_hi(x, 0.f) & 0xffffu);
}
__device__ inline void split2(float x, unsigned short& h, unsigned short& l) {
  h = bf16_1(x);
  l = bf16_1(x - __uint_as_float((unsigned int)h << 16));
}
__device__ inline float bf2f(unsigned short h) {
  return __uint_as_float((unsigned int)h << 16);
}
__device__ inline int swz(int r) { return ((r >> 3) & 7) << 3; }

__device__ inline bf16x8 frag_row(const unsigned short* p, int r, int k0) {
  return *(const bf16x8*)&p[r * ST + (k0 ^ swz(r))];
}
__device__ inline bf16x8 frag_col(const unsigned short* p, int c, int n0) {
  bf16x8 f;
#pragma unroll
  for (int j = 0; j < 8; j++) {
    int n = n0 + j;
    f[j] = (short)p[n * ST + (c ^ swz(n))];
  }
  return f;
}

// ---- prep: stream u once -> colsum slabs (plain stores) + u_bf (bf16) ----
// grid (B, 32), 256 thr; block handles 32 n-rows.
__global__ __launch_bounds__(256) void k_prep(const float* __restrict__ u,
                                              float* __restrict__ cs_part,
                                              unsigned short* __restrict__ u_bf) {
  __shared__ float4 red[128];
  int b = blockIdx.x, ntile = blockIdx.y, n0 = ntile * 32;
  int tid = threadIdx.x;
  int kq = (tid & 127) * 4, ng = tid >> 7;
  const float* ub = u + ((size_t)b * N + n0 + ng * 16) * K + kq;
  unsigned short* ubf = u_bf + ((size_t)b * N + n0 + ng * 16) * K + kq;
  float4 a = {0.f, 0.f, 0.f, 0.f};
#pragma unroll
  for (int nn = 0; nn < 16; nn++) {
    float4 v = *(const float4*)&ub[(size_t)nn * K];
    a.x += v.x; a.y += v.y; a.z += v.z; a.w += v.w;
    uint2 p;
    p.x = pk_hi(v.x, v.y);
    p.y = pk_hi(v.z, v.w);
    *(uint2*)&ubf[(size_t)nn * K] = p;
  }
  if (ng) red[tid & 127] = a;
  __syncthreads();
  if (!ng) {
    float4 o = red[tid];
    float* cs = cs_part + ((size_t)b * 32 + ntile) * K + kq;
    cs[0] = (a.x + o.x) * (1.f / 32.f);
    cs[1] = (a.y + o.y) * (1.f / 32.f);
    cs[2] = (a.z + o.z) * (1.f / 32.f);
    cs[3] = (a.w + o.w) * (1.f / 32.f);
  }
}

// vj[d]=sum_k s[k]W[k,o*64+d] -> ssq_part[slot*1024+bo]; t = W_o@vj bf16 hi/lo.
// slot 0: s = sum of 32 colsum slabs; else sum of 32 bf16 partial-S slabs.
__global__ __launch_bounds__(512) void k_vjt(const unsigned short* __restrict__ Sp,
                                             const float* __restrict__ cs_part,
                                             const float* __restrict__ W,
                                             float* __restrict__ ssq_part, int slot,
                                             unsigned short* __restrict__ t_hi,
                                             unsigned short* __restrict__ t_lo) {
  __shared__ __align__(16) float s_s[K];
  __shared__ float red[7][D];
  __shared__ __align__(16) float vs[D];
  int bo = blockIdx.x, b = bo >> 5, o = bo & 31;
  int d = threadIdx.x & 63, ks = threadIdx.x >> 6;  // 8-way k split
  {
    int i = threadIdx.x;  // 512 threads, one k each
    float a = 0.f;
    if (slot == 0) {
      const float* base = cs_part + (size_t)b * 32 * K;
#pragma unroll
      for (int nt = 0; nt < 32; nt++) a += base[(size_t)nt * K + i];
    } else {
      const unsigned short* base = Sp + ((size_t)b * NT * O + o) * K;
#pragma unroll
      for (int nt = 0; nt < NT; nt++) a += bf2f(base[(size_t)nt * O * K + i]);
    }
    s_s[i] = a;
  }
  __syncthreads();
  float acc = 0.f;
  const float* Wc = W + (size_t)o * D + d;
  for (int k = ks * 64; k < ks * 64 + 64; k += 4) {
    acc += s_s[k] * Wc[(size_t)k * F] + s_s[k + 1] * Wc[(size_t)(k + 1) * F] +
           s_s[k + 2] * Wc[(size_t)(k + 2) * F] + s_s[k + 3] * Wc[(size_t)(k + 3) * F];
  }
  if (ks) red[ks - 1][d] = acc;
  __syncthreads();
  if (ks == 0) {
#pragma unroll
    for (int j = 0; j < 7; j++) acc += red[j][d];
    vs[d] = acc;
    float ss = acc * acc;
#pragma unroll
    for (int m = 32; m >= 1; m >>= 1) ss += __shfl_xor(ss, m, 64);
    if (d == 0) ssq_part[slot * 1024 + bo] = ss;
  }
  __syncthreads();
  {  // t phase: wave handles 64 rows, 8 lanes/row (coalesced W reads)
    int wave = threadIdx.x >> 6, lane = threadIdx.x & 63;
    int rr = lane >> 3, dc = lane & 7;
    float4 va = *(const float4*)&vs[dc * 8];
    float4 vb = *(const float4*)&vs[dc * 8 + 4];
#pragma unroll
    for (int i = 0; i < 8; i++) {
      int kk = wave * 64 + i * 8 + rr;
      const float* Wr = W + (size_t)kk * F + o * 64 + dc * 8;
      float4 wa = *(const float4*)Wr;
      float4 wb = *(const float4*)(Wr + 4);
      float p = wa.x * va.x + wa.y * va.y + wa.z * va.z + wa.w * va.w +
                wb.x * vb.x + wb.y * vb.y + wb.z * vb.z + wb.w * vb.w;
      p += __shfl_xor(p, 1, 64);
      p += __shfl_xor(p, 2, 64);
      p += __shfl_xor(p, 4, 64);
      if (dc == 0) {
        unsigned short h, l;
        split2(p, h, l);
        t_hi[(size_t)bo * K + kk] = h;
        t_lo[(size_t)bo * K + kk] = l;
      }
    }
  }
}

// Final: vj from summed bf16 slabs -> squash -> out
__global__ __launch_bounds__(512) void k_out(const unsigned short* __restrict__ Sp,
                                             const float* __restrict__ W,
                                             float* __restrict__ out) {
  __shared__ __align__(16) float s_s[K];
  __shared__ float red[7][D];
  int bo = blockIdx.x, b = bo >> 5, o = bo & 31;
  int d = threadIdx.x & 63, ks = threadIdx.x >> 6;
  {
    const unsigned short* base = Sp + ((size_t)b * NT * O + o) * K;
    int i = threadIdx.x;
    float a = 0.f;
#pragma unroll
    for (int nt = 0; nt < NT; nt++) a += bf2f(base[(size_t)nt * O * K + i]);
    s_s[i] = a;
  }
  __syncthreads();
  float acc = 0.f;
  const float* Wc = W + (size_t)o * D + d;
  for (int k = ks * 64; k < ks * 64 + 64; k += 4) {
    acc += s_s[k] * Wc[(size_t)k * F] + s_s[k + 1] * Wc[(size_t)(k + 1) * F] +
           s_s[k + 2] * Wc[(size_t)(k + 2) * F] + s_s[k + 3] * Wc[(size_t)(k + 3) * F];
  }
  if (ks) red[ks - 1][d] = acc;
  __syncthreads();
  if (ks == 0) {
#pragma unroll
    for (int j = 0; j < 7; j++) acc += red[j][d];
    float ss = acc * acc;
#pragma unroll
    for (int m = 32; m >= 1; m >>= 1) ss += __shfl_xor(ss, m, 64);
    float s = ss + 1e-7f;
    out[(size_t)bo * D + d] = (sqrtf(s) / (0.5f + s)) * acc;
  }
}

// Fused routing step, 32-n tile, 256 thr (4 waves), grid (B,32)=1024 blocks.
// Staging is pure u16 copy: 256 threads = 32 rows x 8 col-groups, ONE uint4
// each per buffer (fixed: R12 wrote each location twice).
__global__ __launch_bounds__(256, 4) void k_route(const unsigned short* __restrict__ t_hi_g,
                                                  const unsigned short* __restrict__ t_lo_g,
                                                  const unsigned short* __restrict__ u_bf,
                                                  const float* __restrict__ ssq_part,
                                                  int slot,
                                                  unsigned short* __restrict__ Sp) {
  __shared__ unsigned short u_hi[32 * ST];                   // 4608 B
  __shared__ unsigned short t_hi[32 * ST], t_lo[32 * ST];    // 2x4608 B
  __shared__ float wv[32 * 36];                              // 4608 B logits
  __shared__ float psum[8 * 36];                             // softmax partials
  __shared__ float mbuf[36];
  unsigned short* wvh = t_hi;  // alias: t dead after phase 1
  unsigned short* wvl = t_lo;

  const int b = blockIdx.x, n0 = blockIdx.y * 32;
  const int tid = threadIdx.x, lane = tid & 63, wave = tid >> 6;
  const int m = lane & 15, oct = lane >> 4;
  const unsigned short* ubf = u_bf + ((size_t)b * N + n0) * K;
  const unsigned short* thg = t_hi_g + (size_t)b * O * K;
  const unsigned short* tlg = t_lo_g + (size_t)b * O * K;

  // staging index: 32 rows x 8 col-groups of 8 u16 (one uint4 per thread)
  const int sr = tid >> 3, sc8 = (tid & 7) * 8;
  const int scs = sc8 ^ swz(sr);  // swizzled LDS col

  // ---- phase 1: bb[32o][32n] = t . u^T ----
  const int mo = wave & 1, nt = wave >> 1;  // o-half, n-half (16x16 tiles)
  f32x4 accb = {0.f, 0.f, 0.f, 0.f};
  for (int kc = 0; kc < K; kc += 64) {
    __syncthreads();
    {
      const size_t go = (size_t)sr * K + kc + sc8;
      *(uint4*)&t_hi[sr * ST + scs] = *(const uint4*)&thg[go];
      *(uint4*)&t_lo[sr * ST + scs] = *(const uint4*)&tlg[go];
      *(uint4*)&u_hi[sr * ST + scs] = *(const uint4*)&ubf[go];
    }
    __syncthreads();
#pragma unroll
    for (int ks = 0; ks < 64; ks += 32) {
      bf16x8 ah = frag_row(t_hi, mo * 16 + m, ks + oct * 8);
      bf16x8 al = frag_row(t_lo, mo * 16 + m, ks + oct * 8);
      bf16x8 bh = frag_row(u_hi, nt * 16 + m, ks + oct * 8);
      accb = __builtin_amdgcn_mfma_f32_16x16x32_bf16(ah, bh, accb, 0, 0, 0);
      accb = __builtin_amdgcn_mfma_f32_16x16x32_bf16(al, bh, accb, 0, 0, 0);
    }
  }
  __syncthreads();
  // ---- global-norm reduction from ssq_part (1024 entries) ----
  {
    const float* sp = ssq_part + slot * 1024;
    float sa = 0.f;
#pragma unroll
    for (int j = 0; j < 4; j++) sa += sp[tid + j * 256];
    psum[tid & 255] = sa;
    __syncthreads();
    if (tid < 64) {
      float s = psum[tid] + psum[tid + 64] + psum[tid + 128] + psum[tid + 192];
#pragma unroll
      for (int mm = 32; mm >= 1; mm >>= 1) s += __shfl_xor(s, mm, 64);
      if (tid == 0) mbuf[0] = rsqrtf(fmaxf(s, 1e-12f));
    }
    __syncthreads();
  }
  const float nrm_inv = mbuf[0];
  __syncthreads();
#pragma unroll
  for (int r = 0; r < 4; r++)  // D: col=m (n), row=oct*4+r (o)
    wv[(mo * 16 + oct * 4 + r) * 36 + nt * 16 + m] = accb[r] * nrm_inv;
  __syncthreads();

  // ---- softmax over o, parallel: n=tid&31, g=tid>>5 owns 4 o's ----
  {
    int n = tid & 31, g = tid >> 5;
    float m4 = -1e30f;
#pragma unroll
    for (int j = 0; j < 4; j++) m4 = fmaxf(m4, wv[(g * 4 + j) * 36 + n]);
    psum[g * 36 + n] = m4;
    __syncthreads();
    if (tid < 32) {
      float mx = psum[tid];
#pragma unroll
      for (int gg = 1; gg < 8; gg++) mx = fmaxf(mx, psum[gg * 36 + tid]);
      mbuf[tid] = mx;
    }
    __syncthreads();
    float mx = mbuf[n];
    float s4 = 0.f;
#pragma unroll
    for (int j = 0; j < 4; j++) {
      float e = __expf(wv[(g * 4 + j) * 36 + n] - mx);
      wv[(g * 4 + j) * 36 + n] = e;
      s4 += e;
    }
    psum[g * 36 + n] = s4;
    __syncthreads();
    if (tid < 32) {
      float s = 0.f;
#pragma unroll
      for (int gg = 0; gg < 8; gg++) s += psum[gg * 36 + tid];
      mbuf[tid] = 1.f / s;
    }
    __syncthreads();
    float inv = mbuf[n];
#pragma unroll
    for (int j = 0; j < 4; j++) {  // Wv -> bf16 hi/lo into dead t region
      unsigned short h, l;
      split2(wv[(g * 4 + j) * 36 + n] * inv, h, l);
      wvh[(g * 4 + j) * ST + n] = h;
      wvl[(g * 4 + j) * ST + n] = l;
    }
  }
  __syncthreads();

  // ---- phase 2: Spart = Wv . u  (kred = n = 32, bf16 stores, no atomics) ----
  const int mo2 = wave & 1, kp = wave >> 1;  // o-half, ktile-pair
  const int o0 = mo2 * 16;
  bf16x8 a_h = *(const bf16x8*)&wvh[(o0 + m) * ST + oct * 8];
  bf16x8 a_l = *(const bf16x8*)&wvl[(o0 + m) * ST + oct * 8];
  unsigned short* Sb = Sp + ((size_t)b * NT + blockIdx.y) * O * K;
  for (int kc = 0; kc < K; kc += 64) {
    __syncthreads();
    *(uint4*)&u_hi[sr * ST + scs] = *(const uint4*)&ubf[(size_t)sr * K + kc + sc8];
    __syncthreads();
#pragma unroll
    for (int kt = kp * 2; kt < kp * 2 + 2; kt++) {
      int c = kt * 16 + m;  // column within chunk
      bf16x8 bh = frag_col(u_hi, c, oct * 8);
      f32x4 acs = {0.f, 0.f, 0.f, 0.f};
      acs = __builtin_amdgcn_mfma_f32_16x16x32_bf16(a_h, bh, acs, 0, 0, 0);
      acs = __builtin_amdgcn_mfma_f32_16x16x32_bf16(a_l, bh, acs, 0, 0, 0);
#pragma unroll
      for (int r = 0; r < 4; r++)  // D: col=m -> kcol, row=oct*4+r -> o
        Sb[(size_t)(o0 + oct * 4 + r) * K + kc + c] = bf16_1(acs[r]);
    }
  }
}

extern "C" void kernel_launch(void* const* d_in, const int* in_sizes, int n_in,
                              void* d_out, int out_size, void* d_ws, size_t ws_size,
                              hipStream_t stream) {
  const float* u = (const float*)d_in[0];  // [B,N,K] f32
  const float* W = (const float*)d_in[1];  // [K,F] f32
  float* out = (float*)d_out;              // [B,O,D] f32

  char* ws = (char*)d_ws;
  unsigned short* Sp = (unsigned short*)ws;              // B*NT*O*K u16 (33.5MB)
  unsigned short* u_bf = Sp + (size_t)B * NT * O * K;    // B*N*K u16 (33.5MB)
  unsigned short* t_hi = u_bf + (size_t)B * N * K;       // B*O*K u16 (1MB)
  unsigned short* t_lo = t_hi + (size_t)B * O * K;       // B*O*K u16
  float* cs_part = (float*)(t_lo + (size_t)B * O * K);   // B*32*K f32 (2MB)
  float* ssq_part = cs_part + (size_t)B * 32 * K;        // 2048 f32

  k_prep<<<dim3(B, 32), 256, 0, stream>>>(u, cs_part, u_bf);
  k_vjt<<<B * O, 512, 0, stream>>>(Sp, cs_part, W, ssq_part, 0, t_hi, t_lo);
  k_route<<<dim3(B, NT), 256, 0, stream>>>(t_hi, t_lo, u_bf, ssq_part, 0, Sp);
  k_vjt<<<B * O, 512, 0, stream>>>(Sp, cs_part, W, ssq_part, 1, t_hi, t_lo);
  k_route<<<dim3(B, NT), 256, 0, stream>>>(t_hi, t_lo, u_bf, ssq_part, 1, Sp);
  k_out<<<B * O, 512, 0, stream>>>(Sp, W, out);
}